// Round 3
// baseline (1809.733 us; speedup 1.0000x reference)
//
#include <hip/hip_runtime.h>
#include <hip/hip_bf16.h>

// DirectVoxGO forward: trilinear density -> alpha -> per-ray cumprod ->
// trilinear 7ch feature -> MLP(34->16 relu ->3 sigmoid) -> weighted march.
// Inputs fp32, output fp32 (R2 post-mortem: absmax==stub value proved the
// fp32 output buffer was half-written by bf16 ushort stores).

#define G 256
#define G2 65536
#define G3 16777216
#define ACT_SHIFT (-4.5951198501345898f)   // log(1/(1-0.01)-1) = -ln(99)

__device__ __forceinline__ float trilerp(const float* __restrict__ g,
                                         int base, float fx, float fy, float fz) {
    float c000 = g[base];
    float c001 = g[base + 1];
    float c010 = g[base + G];
    float c011 = g[base + G + 1];
    float c100 = g[base + G2];
    float c101 = g[base + G2 + 1];
    float c110 = g[base + G2 + G];
    float c111 = g[base + G2 + G + 1];
    float c00 = c000 + fz * (c001 - c000);
    float c01 = c010 + fz * (c011 - c010);
    float c10 = c100 + fz * (c111 - c110) * 0.0f + fz * (c101 - c100); // keep simple form below
    float c11 = c110 + fz * (c111 - c110);
    c10 = c100 + fz * (c101 - c100);
    float c0 = c00 + fy * (c01 - c00);
    float c1 = c10 + fy * (c11 - c10);
    return c0 + fx * (c1 - c0);
}

__global__ __launch_bounds__(256)
void dvgo_fwd(const float* __restrict__ rays_pts,
              const float* __restrict__ viewdirs,
              const float* __restrict__ density,
              const float* __restrict__ k0,
              const float* __restrict__ w1,
              const float* __restrict__ b1,
              const float* __restrict__ w2,
              const float* __restrict__ b2,
              float* __restrict__ out,
              int n_rays) {
    __shared__ float s_w1[34 * 16];
    __shared__ float s_b1[16];
    __shared__ float s_w2[48];
    __shared__ float s_b2[3];

    const int tid = threadIdx.x;
    for (int i = tid; i < 34 * 16; i += 256) s_w1[i] = w1[i];
    if (tid < 16) s_b1[tid] = b1[tid];
    if (tid < 48) s_w2[tid] = w2[tid];
    if (tid < 3)  s_b2[tid] = b2[tid];
    __syncthreads();

    const int lane = tid & 63;
    const int ray  = blockIdx.x * 4 + (tid >> 6);   // one wave per ray
    if (ray >= n_rays) return;

    // ---- phase 1: 4 samples/lane (samples lane*4+k), density -> alpha ----
    const float4* pp4 = (const float4*)(rays_pts + (size_t)ray * (256 * 3) + lane * 12);
    float4 p0 = pp4[0];   // s0.xyz, s1.x
    float4 p1 = pp4[1];   // s1.yz, s2.xy
    float4 p2 = pp4[2];   // s2.z, s3.xyz
    float px[4] = {p0.x, p0.w, p1.z, p2.y};
    float py[4] = {p0.y, p1.x, p1.w, p2.z};
    float pz[4] = {p0.z, p1.y, p2.x, p2.w};

    int   base[4];
    float fx[4], fy[4], fz[4], alpha[4], tcl[4];
    #pragma unroll
    for (int k = 0; k < 4; ++k) {
        float gx = fminf(fmaxf((px[k] + 1.0f) * 127.5f, 0.0f), 255.0f);
        float gy = fminf(fmaxf((py[k] + 1.0f) * 127.5f, 0.0f), 255.0f);
        float gz = fminf(fmaxf((pz[k] + 1.0f) * 127.5f, 0.0f), 255.0f);
        int ix = min((int)gx, 254);
        int iy = min((int)gy, 254);
        int iz = min((int)gz, 254);
        fx[k] = gx - (float)ix;
        fy[k] = gy - (float)iy;
        fz[k] = gz - (float)iz;
        base[k] = (ix << 16) + (iy << 8) + iz;
        float sigma = trilerp(density, base[k], fx[k], fy[k], fz[k]);
        float x = sigma + ACT_SHIFT;
        float sp = fmaxf(x, 0.0f) + log1pf(expf(-fabsf(x)));  // stable softplus
        float t = expf(-sp);                 // = 1 - alpha
        alpha[k] = 1.0f - t;
        tcl[k] = fmaxf(t, 1e-10f);
    }

    // ---- phase 2: exclusive cumprod of tcl across the 256-sample ray ----
    float A[4];
    float lp = 1.0f;
    #pragma unroll
    for (int k = 0; k < 4; ++k) { A[k] = lp; lp *= tcl[k]; }
    float inc = lp;                          // inclusive scan over lane totals
    #pragma unroll
    for (int off = 1; off < 64; off <<= 1) {
        float y = __shfl_up(inc, off, 64);
        if (lane >= off) inc *= y;
    }
    float totalT = __shfl(inc, 63, 64);      // alphainv_cum[..., -1]
    float excl = __shfl_up(inc, 1, 64);
    if (lane == 0) excl = 1.0f;
    float weff[4];
    #pragma unroll
    for (int k = 0; k < 4; ++k) {
        float w = alpha[k] * (A[k] * excl);
        weff[k] = (w > 1e-4f) ? w : 0.0f;    // FAST_COLOR_THRES
    }

    // ---- phase 3: per-ray view-embedding contribution to layer 1 ----
    float vd[3] = {viewdirs[ray * 3 + 0], viewdirs[ray * 3 + 1], viewdirs[ray * 3 + 2]};
    float hpre[16];
    #pragma unroll
    for (int j = 0; j < 16; ++j) hpre[j] = s_b1[j];
    #pragma unroll
    for (int d = 0; d < 3; ++d) {
        #pragma unroll
        for (int j = 0; j < 16; ++j) hpre[j] += vd[d] * s_w1[(7 + d) * 16 + j];
    }
    #pragma unroll
    for (int d = 0; d < 3; ++d) {
        #pragma unroll
        for (int fi = 0; fi < 4; ++fi) {
            float a = vd[d] * (float)(1 << fi);
            float sv = sinf(a);
            float cv = cosf(a);
            const int rs = (10 + d * 4 + fi) * 16;
            const int rc = (22 + d * 4 + fi) * 16;
            #pragma unroll
            for (int j = 0; j < 16; ++j)
                hpre[j] += sv * s_w1[rs + j] + cv * s_w1[rc + j];
        }
    }

    // ---- phase 4: feature gather + MLP + march for visible samples ----
    float acc0 = 0.0f, acc1 = 0.0f, acc2 = 0.0f;
    #pragma unroll
    for (int k = 0; k < 4; ++k) {
        if (weff[k] <= 0.0f) continue;
        float h[16];
        #pragma unroll
        for (int j = 0; j < 16; ++j) h[j] = hpre[j];
        #pragma unroll
        for (int c = 0; c < 7; ++c) {
            float f = trilerp(k0 + (size_t)c * G3, base[k], fx[k], fy[k], fz[k]);
            #pragma unroll
            for (int j = 0; j < 16; ++j) h[j] += f * s_w1[c * 16 + j];
        }
        float r0 = s_b2[0], r1 = s_b2[1], r2 = s_b2[2];
        #pragma unroll
        for (int j = 0; j < 16; ++j) {
            float hj = fmaxf(h[j], 0.0f);
            r0 += hj * s_w2[j * 3 + 0];
            r1 += hj * s_w2[j * 3 + 1];
            r2 += hj * s_w2[j * 3 + 2];
        }
        r0 = 1.0f / (1.0f + expf(-r0));
        r1 = 1.0f / (1.0f + expf(-r1));
        r2 = 1.0f / (1.0f + expf(-r2));
        acc0 += weff[k] * r0;
        acc1 += weff[k] * r1;
        acc2 += weff[k] * r2;
    }

    // ---- phase 5: wave reduction + output ----
    #pragma unroll
    for (int off = 32; off > 0; off >>= 1) {
        acc0 += __shfl_down(acc0, off, 64);
        acc1 += __shfl_down(acc1, off, 64);
        acc2 += __shfl_down(acc2, off, 64);
    }
    if (lane == 0) {
        out[ray * 3 + 0] = acc0 + totalT;
        out[ray * 3 + 1] = acc1 + totalT;
        out[ray * 3 + 2] = acc2 + totalT;
    }
}

extern "C" void kernel_launch(void* const* d_in, const int* in_sizes, int n_in,
                              void* d_out, int out_size, void* d_ws, size_t ws_size,
                              hipStream_t stream) {
    const float* rays_pts = (const float*)d_in[0];
    const float* viewdirs = (const float*)d_in[1];
    const float* density  = (const float*)d_in[2];
    const float* k0       = (const float*)d_in[3];
    const float* w1       = (const float*)d_in[4];
    const float* b1       = (const float*)d_in[5];
    const float* w2       = (const float*)d_in[6];
    const float* b2       = (const float*)d_in[7];
    float* out = (float*)d_out;

    int n_rays = in_sizes[1] / 3;            // viewdirs is [Nr, 3]
    int blocks = (n_rays + 3) / 4;           // 4 rays (waves) per 256-thread block
    dvgo_fwd<<<blocks, 256, 0, stream>>>(rays_pts, viewdirs, density, k0,
                                         w1, b1, w2, b2, out, n_rays);
}